// Round 6
// baseline (80.986 us; speedup 1.0000x reference)
//
#include <hip/hip_runtime.h>
#include <hip/hip_bf16.h>
#include <stdint.h>

// Causal SDPA, B=2 H=16 S=2048 DK=64, fp32 in/out, bf16 MFMA compute.
// R6: split-K for occupancy. Each q-tile pair (qt_a+qt_b=31) is handled by
// TWO blocks (even/odd kv tiles) -> 1024 blocks x 4 waves = 16 waves/CU.
// exp2-direct softmax (no max shift) makes the merge exact: O and l combine
// by atomicAdd (2 contributions/address -> bitwise deterministic), then a
// normalize kernel divides. Prepass -> bf16 pre-swizzled ws tiles (unchanged).

#define SEQ   2048
#define DKK   64
#define KVB   64
#define NKT   (SEQ / KVB)    // 32
#define TILE_BYTES 16384     // 8KB K-swz + 8KB Vt-swz
#define WS_TILES ((size_t)32 * NKT * TILE_BYTES)        // 16 MB
#define L_BYTES  ((size_t)32 * SEQ * 4)                 // 256 KB
#define WS_NEED  WS_TILES
#define WS_NEED2 (WS_TILES + L_BYTES)

typedef float  f32x4  __attribute__((ext_vector_type(4)));
typedef short  s16x8  __attribute__((ext_vector_type(8)));
typedef short  s16x4  __attribute__((ext_vector_type(4)));
typedef __bf16 bf16x8 __attribute__((ext_vector_type(8)));

static __device__ __forceinline__ unsigned short f2b(float x) {
  union { float f; uint32_t u; } v; v.f = x;
  uint32_t r = v.u + 0x7fffu + ((v.u >> 16) & 1u);   // RNE bf16
  return (unsigned short)(r >> 16);
}

// Row-major [rows][64] bf16 tile, 128B rows, XOR chunk swizzle ^ (row&7).
static __device__ __forceinline__ int swzA(int row, int col) {
  return row * 128 + ((((col >> 3) ^ (row & 7)) << 4)) + ((col & 7) << 1);
}
// Vt [d][kv] bf16, swizzle ^ ((d>>1)&7).
static __device__ __forceinline__ int swzV(int d, int kv) {
  return d * 128 + ((((kv >> 3) ^ ((d >> 1) & 7)) << 4)) + ((kv & 7) << 1);
}

// ---------------- prepass: K/V fp32 -> bf16 swizzled tile images in ws ------
__global__ __launch_bounds__(256)
void prep_kv(const float* __restrict__ Kg, const float* __restrict__ Vg,
             char* __restrict__ ws) {
  const int b   = blockIdx.x;          // bh*32 + kt, 1024 blocks
  const int bh  = b >> 5, kt = b & 31;
  const int tid = threadIdx.x;
  char* tile = ws + ((size_t)b << 14);
  const size_t base = ((size_t)bh * SEQ + (size_t)kt * KVB) * DKK;
  const float* Kb = Kg + base;
  const float* Vb = Vg + base;
  {
    int col4 = tid & 15, rq = tid >> 4;
#pragma unroll
    for (int ii = 0; ii < 4; ++ii) {
      int row = ii * 16 + rq;
      f32x4 v = *(const f32x4*)(Kb + (size_t)row * DKK + col4 * 4);
      s16x4 w; w[0]=f2b(v[0]); w[1]=f2b(v[1]); w[2]=f2b(v[2]); w[3]=f2b(v[3]);
      *(s16x4*)(tile + swzA(row, col4 * 4)) = w;
    }
  }
  {
    int d0 = (tid & 15) * 4, kv0 = (tid >> 4) * 4;
    f32x4 vv[4];
#pragma unroll
    for (int r2 = 0; r2 < 4; ++r2)
      vv[r2] = *(const f32x4*)(Vb + (size_t)(kv0 + r2) * DKK + d0);
#pragma unroll
    for (int j = 0; j < 4; ++j) {
      s16x4 w; w[0]=f2b(vv[0][j]); w[1]=f2b(vv[1][j]); w[2]=f2b(vv[2][j]); w[3]=f2b(vv[3][j]);
      *(s16x4*)(tile + 8192 + swzV(d0 + j, kv0)) = w;
    }
  }
}

// ---------------- main: split-K paired q-tiles, atomic merge ----------------
__global__ __launch_bounds__(256, 4)
void attn_fwd6(const float* __restrict__ Qg, const char* __restrict__ ws,
               float* __restrict__ lws, float* __restrict__ Og) {
  // LDS: [K 8KB | Vt 8KB] tile | P 4 x 2KB (per wave) = 24KB
  __shared__ __align__(16) char smem[TILE_BYTES + 4 * 2048];

  const int tid  = threadIdx.x;
  const int lane = tid & 63;
  const int wave = tid >> 6;
  const int c    = lane & 15;
  const int g    = lane >> 4;

  // decode: 1024 blocks = 8 xcd x 4 bh x 16 pairs x 2 halves
  const int f      = blockIdx.x;
  const int xcd    = f & 7;
  const int inner  = f >> 3;               // 0..127
  const int half   = inner & 1;            // kv-tile parity
  const int inner2 = inner >> 1;           // 0..63
  const int bh     = ((inner2 >> 4) << 3) | xcd;
  const int p      = inner2 & 15;
  const int qt_a   = 31 - p;               // 16..31
  const int qt_b   = p;                    // 0..15
  const int nkt_a  = qt_a + 1;
  const int nkt_b  = qt_b + 1;

  const float CS = 0.18033688011f;         // (1/sqrt(64)) * log2(e)
  const size_t bhoff = (size_t)bh * SEQ * DKK;
  const float* Qb = Qg + bhoff;
  float*       Ob = Og + bhoff;
  float*       lbh = lws + bh * SEQ;
  const char*  wsb = ws + ((size_t)bh * NKT << 14);

  // prologue: load first tile of this parity into registers
  {
  }
  const char* t0p = wsb + ((size_t)half << 14);
  s16x8 stA0 = *(const s16x8*)(t0p + tid * 16);
  s16x8 stA1 = *(const s16x8*)(t0p + 4096 + tid * 16);
  s16x8 stB0 = *(const s16x8*)(t0p + 8192 + tid * 16);
  s16x8 stB1 = *(const s16x8*)(t0p + 12288 + tid * 16);

  // Q fragments (scale folded): row = qt*64 + wave*16 + c, k = h*32 + g*8 + j
  s16x8 qfA[2], qfB[2];
#pragma unroll
  for (int h = 0; h < 2; ++h) {
    int d0 = h * 32 + g * 8;
    {
      const f32x4* pq = (const f32x4*)(Qb + (size_t)(qt_a * 64 + wave * 16 + c) * DKK + d0);
      f32x4 a = pq[0], b = pq[1];
      s16x8 r;
      r[0]=f2b(a[0]*CS); r[1]=f2b(a[1]*CS); r[2]=f2b(a[2]*CS); r[3]=f2b(a[3]*CS);
      r[4]=f2b(b[0]*CS); r[5]=f2b(b[1]*CS); r[6]=f2b(b[2]*CS); r[7]=f2b(b[3]*CS);
      qfA[h] = r;
    }
    {
      const f32x4* pq = (const f32x4*)(Qb + (size_t)(qt_b * 64 + wave * 16 + c) * DKK + d0);
      f32x4 a = pq[0], b = pq[1];
      s16x8 r;
      r[0]=f2b(a[0]*CS); r[1]=f2b(a[1]*CS); r[2]=f2b(a[2]*CS); r[3]=f2b(a[3]*CS);
      r[4]=f2b(b[0]*CS); r[5]=f2b(b[1]*CS); r[6]=f2b(b[2]*CS); r[7]=f2b(b[3]*CS);
      qfB[h] = r;
    }
  }

  s16x8 ones8;
#pragma unroll
  for (int j = 0; j < 8; ++j) ones8[j] = (short)0x3F80;

  f32x4 OA[4] = {}, OB[4] = {};
  f32x4 OlA = {}, OlB = {};

  char* Kl = smem;
  char* Vl = smem + 8192;
  char* Pl = smem + TILE_BYTES + wave * 2048;

  auto compute_tile = [&](const s16x8* qf, f32x4* O, f32x4& Ol, bool domask) {
    f32x4 S[4] = {};
    __builtin_amdgcn_s_setprio(1);
#pragma unroll
    for (int s = 0; s < 4; ++s)
#pragma unroll
      for (int h = 0; h < 2; ++h) {
        s16x8 kf = *(const s16x8*)(Kl + swzA(s * 16 + c, h * 32 + g * 8));
        S[s] = __builtin_amdgcn_mfma_f32_16x16x32_bf16(
            __builtin_bit_cast(bf16x8, qf[h]),
            __builtin_bit_cast(bf16x8, kf), S[s], 0, 0, 0);
      }
    __builtin_amdgcn_s_setprio(0);

    if (domask) {                       // diagonal tile: kv > qrow -> -inf
      int qrl = wave * 16 + g * 4;
#pragma unroll
      for (int s = 0; s < 4; ++s) {
        int kvl = s * 16 + c;
#pragma unroll
        for (int r = 0; r < 4; ++r)
          if (kvl > qrl + r) S[s][r] = -1e30f;
      }
    }

#pragma unroll
    for (int r = 0; r < 4; ++r)
#pragma unroll
      for (int s = 0; s < 4; ++s) {
        float pv = exp2f(S[s][r]);
        *(unsigned short*)(Pl + swzA(g * 4 + r, s * 16 + c)) = f2b(pv);
      }

    __builtin_amdgcn_s_setprio(1);
#pragma unroll
    for (int ch = 0; ch < 2; ++ch) {
      s16x8 pa = *(const s16x8*)(Pl + swzA(c, ch * 32 + g * 8));
#pragma unroll
      for (int t = 0; t < 4; ++t) {
        s16x8 vb = *(const s16x8*)(Vl + swzV(t * 16 + c, ch * 32 + g * 8));
        O[t] = __builtin_amdgcn_mfma_f32_16x16x32_bf16(
            __builtin_bit_cast(bf16x8, pa),
            __builtin_bit_cast(bf16x8, vb), O[t], 0, 0, 0);
      }
      Ol = __builtin_amdgcn_mfma_f32_16x16x32_bf16(
          __builtin_bit_cast(bf16x8, pa),
          __builtin_bit_cast(bf16x8, ones8), Ol, 0, 0, 0);
    }
    __builtin_amdgcn_s_setprio(0);
  };

  for (int kt = half; kt < nkt_a; kt += 2) {
    __syncthreads();                       // (a) prev-iter LDS reads done
    *(s16x8*)(smem + tid * 16)         = stA0;
    *(s16x8*)(smem + 4096 + tid * 16)  = stA1;
    *(s16x8*)(smem + 8192 + tid * 16)  = stB0;
    *(s16x8*)(smem + 12288 + tid * 16) = stB1;
    if (kt + 2 < nkt_a) {                  // prefetch next same-parity tile
      const char* tn = wsb + ((size_t)(kt + 2) << 14);
      stA0 = *(const s16x8*)(tn + tid * 16);
      stA1 = *(const s16x8*)(tn + 4096 + tid * 16);
      stB0 = *(const s16x8*)(tn + 8192 + tid * 16);
      stB1 = *(const s16x8*)(tn + 12288 + tid * 16);
    }
    __syncthreads();                       // (b) staged tile visible

    compute_tile(qfA, OA, OlA, kt == qt_a);
    if (kt < nkt_b)
      compute_tile(qfB, OB, OlB, kt == qt_b);
  }

  // epilogue: atomic merge of the two kv-parity halves (exact: 2 contribs)
#pragma unroll
  for (int r = 0; r < 4; ++r) {
    int qra = qt_a * 64 + wave * 16 + g * 4 + r;
    int qrb = qt_b * 64 + wave * 16 + g * 4 + r;
#pragma unroll
    for (int t = 0; t < 4; ++t) {
      atomicAdd(&Ob[(size_t)qra * DKK + t * 16 + c], OA[t][r]);
      atomicAdd(&Ob[(size_t)qrb * DKK + t * 16 + c], OB[t][r]);
    }
    if (c == 0) {
      atomicAdd(&lbh[qra], OlA[r]);
      atomicAdd(&lbh[qrb], OlB[r]);
    }
  }
}

// ---------------- normalize: O /= l ----------------------------------------
__global__ __launch_bounds__(256)
void norm_out(float* __restrict__ Og, const float* __restrict__ lws) {
  const int gid = blockIdx.x * 256 + threadIdx.x;
  const size_t base = (size_t)gid * 8;       // 8 floats/thread, same row
  const int row = (int)(base >> 6);          // bh*2048 + qrow
  float inv = 1.f / lws[row];
  f32x4* p = (f32x4*)(Og + base);
  f32x4 a = p[0], b = p[1];
#pragma unroll
  for (int j = 0; j < 4; ++j) { a[j] *= inv; b[j] *= inv; }
  p[0] = a; p[1] = b;
}

// ---------------- R5 path (fallback if l-array doesn't fit) -----------------
__global__ __launch_bounds__(256, 2)
void attn_fwd5(const float* __restrict__ Qg, const char* __restrict__ ws,
               float* __restrict__ Og) {
  __shared__ __align__(16) char smem[TILE_BYTES + 4 * 2048];
  const int tid  = threadIdx.x;
  const int lane = tid & 63;
  const int wave = tid >> 6;
  const int c    = lane & 15;
  const int g    = lane >> 4;
  const int f     = blockIdx.x;
  const int xcd   = f & 7;
  const int inner = f >> 3;
  const int bh    = ((inner >> 4) << 3) | xcd;
  const int p     = inner & 15;
  const int qt_a  = 31 - p;
  const int qt_b  = p;
  const int nkt_a = qt_a + 1;
  const int nkt_b = qt_b + 1;
  const float CS = 0.18033688011f;
  const size_t bhoff = (size_t)bh * SEQ * DKK;
  const float* Qb = Qg + bhoff;
  float*       Ob = Og + bhoff;
  const char*  wsb = ws + ((size_t)bh * NKT << 14);
  s16x8 stA0 = *(const s16x8*)(wsb + tid * 16);
  s16x8 stA1 = *(const s16x8*)(wsb + 4096 + tid * 16);
  s16x8 stB0 = *(const s16x8*)(wsb + 8192 + tid * 16);
  s16x8 stB1 = *(const s16x8*)(wsb + 12288 + tid * 16);
  s16x8 qfA[2], qfB[2];
#pragma unroll
  for (int h = 0; h < 2; ++h) {
    int d0 = h * 32 + g * 8;
    {
      const f32x4* pq = (const f32x4*)(Qb + (size_t)(qt_a * 64 + wave * 16 + c) * DKK + d0);
      f32x4 a = pq[0], b = pq[1];
      s16x8 r;
      r[0]=f2b(a[0]*CS); r[1]=f2b(a[1]*CS); r[2]=f2b(a[2]*CS); r[3]=f2b(a[3]*CS);
      r[4]=f2b(b[0]*CS); r[5]=f2b(b[1]*CS); r[6]=f2b(b[2]*CS); r[7]=f2b(b[3]*CS);
      qfA[h] = r;
    }
    {
      const f32x4* pq = (const f32x4*)(Qb + (size_t)(qt_b * 64 + wave * 16 + c) * DKK + d0);
      f32x4 a = pq[0], b = pq[1];
      s16x8 r;
      r[0]=f2b(a[0]*CS); r[1]=f2b(a[1]*CS); r[2]=f2b(a[2]*CS); r[3]=f2b(a[3]*CS);
      r[4]=f2b(b[0]*CS); r[5]=f2b(b[1]*CS); r[6]=f2b(b[2]*CS); r[7]=f2b(b[3]*CS);
      qfB[h] = r;
    }
  }
  s16x8 ones8;
#pragma unroll
  for (int j = 0; j < 8; ++j) ones8[j] = (short)0x3F80;
  f32x4 OA[4] = {}, OB[4] = {};
  f32x4 OlA = {}, OlB = {};
  char* Kl = smem;
  char* Vl = smem + 8192;
  char* Pl = smem + TILE_BYTES + wave * 2048;
  auto compute_tile = [&](const s16x8* qf, f32x4* O, f32x4& Ol, bool domask) {
    f32x4 S[4] = {};
#pragma unroll
    for (int s = 0; s < 4; ++s)
#pragma unroll
      for (int h = 0; h < 2; ++h) {
        s16x8 kf = *(const s16x8*)(Kl + swzA(s * 16 + c, h * 32 + g * 8));
        S[s] = __builtin_amdgcn_mfma_f32_16x16x32_bf16(
            __builtin_bit_cast(bf16x8, qf[h]),
            __builtin_bit_cast(bf16x8, kf), S[s], 0, 0, 0);
      }
    if (domask) {
      int qrl = wave * 16 + g * 4;
#pragma unroll
      for (int s = 0; s < 4; ++s) {
        int kvl = s * 16 + c;
#pragma unroll
        for (int r = 0; r < 4; ++r)
          if (kvl > qrl + r) S[s][r] = -1e30f;
      }
    }
#pragma unroll
    for (int r = 0; r < 4; ++r)
#pragma unroll
      for (int s = 0; s < 4; ++s) {
        float pv = exp2f(S[s][r]);
        *(unsigned short*)(Pl + swzA(g * 4 + r, s * 16 + c)) = f2b(pv);
      }
#pragma unroll
    for (int ch = 0; ch < 2; ++ch) {
      s16x8 pa = *(const s16x8*)(Pl + swzA(c, ch * 32 + g * 8));
#pragma unroll
      for (int t = 0; t < 4; ++t) {
        s16x8 vb = *(const s16x8*)(Vl + swzV(t * 16 + c, ch * 32 + g * 8));
        O[t] = __builtin_amdgcn_mfma_f32_16x16x32_bf16(
            __builtin_bit_cast(bf16x8, pa),
            __builtin_bit_cast(bf16x8, vb), O[t], 0, 0, 0);
      }
      Ol = __builtin_amdgcn_mfma_f32_16x16x32_bf16(
          __builtin_bit_cast(bf16x8, pa),
          __builtin_bit_cast(bf16x8, ones8), Ol, 0, 0, 0);
    }
  };
  for (int kt = 0; kt < nkt_a; ++kt) {
    __syncthreads();
    *(s16x8*)(smem + tid * 16)         = stA0;
    *(s16x8*)(smem + 4096 + tid * 16)  = stA1;
    *(s16x8*)(smem + 8192 + tid * 16)  = stB0;
    *(s16x8*)(smem + 12288 + tid * 16) = stB1;
    if (kt + 1 < nkt_a) {
      const char* tn = wsb + ((size_t)(kt + 1) << 14);
      stA0 = *(const s16x8*)(tn + tid * 16);
      stA1 = *(const s16x8*)(tn + 4096 + tid * 16);
      stB0 = *(const s16x8*)(tn + 8192 + tid * 16);
      stB1 = *(const s16x8*)(tn + 12288 + tid * 16);
    }
    __syncthreads();
    compute_tile(qfA, OA, OlA, kt == qt_a);
    if (kt < nkt_b)
      compute_tile(qfB, OB, OlB, kt == qt_b);
  }
#pragma unroll
  for (int r = 0; r < 4; ++r) {
    int qra = qt_a * 64 + wave * 16 + g * 4 + r;
    int qrb = qt_b * 64 + wave * 16 + g * 4 + r;
    float ia = 1.f / OlA[r];
    float ib = 1.f / OlB[r];
#pragma unroll
    for (int t = 0; t < 4; ++t) {
      Ob[(size_t)qra * DKK + t * 16 + c] = OA[t][r] * ia;
      Ob[(size_t)qrb * DKK + t * 16 + c] = OB[t][r] * ib;
    }
  }
}

extern "C" void kernel_launch(void* const* d_in, const int* in_sizes, int n_in,
                              void* d_out, int out_size, void* d_ws, size_t ws_size,
                              hipStream_t stream) {
  const float* Q = (const float*)d_in[0];
  const float* K = (const float*)d_in[1];
  const float* V = (const float*)d_in[2];
  float* O = (float*)d_out;
  (void)in_sizes; (void)n_in;
  char* ws = (char*)d_ws;
  if (ws_size >= WS_NEED2) {
    float* lws = (float*)(ws + WS_TILES);
    hipMemsetAsync(d_out, 0, (size_t)out_size * sizeof(float), stream);
    hipMemsetAsync(lws, 0, L_BYTES, stream);
    prep_kv<<<dim3(32 * NKT), dim3(256), 0, stream>>>(K, V, ws);
    attn_fwd6<<<dim3(1024), dim3(256), 0, stream>>>(Q, ws, lws, O);
    norm_out<<<dim3((unsigned)(((size_t)out_size / 8 + 255) / 256)), dim3(256), 0, stream>>>(O, lws);
  } else {
    prep_kv<<<dim3(32 * NKT), dim3(256), 0, stream>>>(K, V, ws);
    attn_fwd5<<<dim3(512), dim3(256), 0, stream>>>(Q, ws, O);
  }
}

// Round 8
// 65.427 us; speedup vs baseline: 1.2378x; 1.2378x over previous
//
#include <hip/hip_runtime.h>
#include <hip/hip_bf16.h>
#include <stdint.h>

// Causal SDPA, B=2 H=16 S=2048 DK=64, fp32 in/out, bf16 MFMA compute.
// R8 = R7 with corrected packed-P LDS layout.
// 512 blocks x 4 waves; block owns q-tile pair (qt_a+qt_b=31). Wave=(wq,wk):
// wq -> 2 q-subtiles of BOTH tiles, wk -> 32-wide kv half. K/V frags shared
// across 4 q-subtiles; P packed 2 bf16/ds_write_b32 (kv pos-interleaved,
// V permuted identically in prepass so A/B contraction perms match).
// O partials over kv halves merge exactly (exp2-direct softmax) via LDS
// reduction in epilogue. P slot layout:
//   addr(row,pos) = row*64 + ((pos*2) ^ ((row&3)<<4) ^ (((row>>2)&1)<<5))

#define SEQ   2048
#define DKK   64
#define KVB   64
#define NKT   (SEQ / KVB)    // 32
#define TILE_BYTES 16384     // 8KB K-swz + 8KB Vt-swz(perm)
#define WS_NEED ((size_t)32 * NKT * TILE_BYTES)   // 16 MB

typedef float  f32x4  __attribute__((ext_vector_type(4)));
typedef short  s16x8  __attribute__((ext_vector_type(8)));
typedef short  s16x4  __attribute__((ext_vector_type(4)));
typedef __bf16 bf16x8 __attribute__((ext_vector_type(8)));

static __device__ __forceinline__ unsigned short f2b(float x) {
  union { float f; uint32_t u; } v; v.f = x;
  uint32_t r = v.u + 0x7fffu + ((v.u >> 16) & 1u);   // RNE bf16
  return (unsigned short)(r >> 16);
}

// Row-major [rows][64] bf16 tile, 128B rows, XOR chunk swizzle ^ (row&7).
static __device__ __forceinline__ int swzA(int row, int col) {
  return row * 128 + ((((col >> 3) ^ (row & 7)) << 4)) + ((col & 7) << 1);
}
// Vt [d][pos] bf16 (pos = permuted kv), swizzle ^ ((d>>1)&7).
static __device__ __forceinline__ int swzV(int d, int pos) {
  return d * 128 + ((((pos >> 3) ^ ((d >> 1) & 7)) << 4)) + ((pos & 7) << 1);
}

// ---------------- prepass: K/V fp32 -> bf16 swizzled tile images in ws ------
// V kv-order permuted within each 32-half: pos = half*32 + (kvh&15)*2 + (kvh>>4)
__global__ __launch_bounds__(256)
void prep_kv(const float* __restrict__ Kg, const float* __restrict__ Vg,
             char* __restrict__ ws) {
  const int b   = blockIdx.x;          // bh*32 + kt, 1024 blocks
  const int bh  = b >> 5, kt = b & 31;
  const int tid = threadIdx.x;
  char* tile = ws + ((size_t)b << 14);
  const size_t base = ((size_t)bh * SEQ + (size_t)kt * KVB) * DKK;
  const float* Kb = Kg + base;
  const float* Vb = Vg + base;
  // K: row-major swizzled
  {
    int col4 = tid & 15, rq = tid >> 4;
#pragma unroll
    for (int ii = 0; ii < 4; ++ii) {
      int row = ii * 16 + rq;
      f32x4 v = *(const f32x4*)(Kb + (size_t)row * DKK + col4 * 4);
      s16x4 w; w[0]=f2b(v[0]); w[1]=f2b(v[1]); w[2]=f2b(v[2]); w[3]=f2b(v[3]);
      *(s16x4*)(tile + swzA(row, col4 * 4)) = w;
    }
  }
  // V: transposed + kv->pos permuted
  {
    int d0 = (tid & 15) * 4, pos0 = (tid >> 4) * 4;
    int half = pos0 >> 5, p0 = pos0 & 31;
    int kvb = half * 32 + (p0 >> 1);
    // pos0+i -> kv rows: {kvb, kvb+16, kvb+1, kvb+17}
    f32x4 vv[4];
    vv[0] = *(const f32x4*)(Vb + (size_t)(kvb)      * DKK + d0);
    vv[1] = *(const f32x4*)(Vb + (size_t)(kvb + 16) * DKK + d0);
    vv[2] = *(const f32x4*)(Vb + (size_t)(kvb + 1)  * DKK + d0);
    vv[3] = *(const f32x4*)(Vb + (size_t)(kvb + 17) * DKK + d0);
#pragma unroll
    for (int j = 0; j < 4; ++j) {
      s16x4 w; w[0]=f2b(vv[0][j]); w[1]=f2b(vv[1][j]); w[2]=f2b(vv[2][j]); w[3]=f2b(vv[3][j]);
      *(s16x4*)(tile + 8192 + swzV(d0 + j, pos0)) = w;
    }
  }
}

// ---------------- main: 4-wave (2 q-groups x 2 kv-halves), paired q-tiles ---
__global__ __launch_bounds__(256, 2)
void attn_fwd8(const float* __restrict__ Qg, const char* __restrict__ ws,
               float* __restrict__ Og) {
  // LDS: [K 8KB | Vt 8KB] tile | P 4 waves x 4KB = 32KB
  __shared__ __align__(16) char smem[TILE_BYTES + 4 * 4096];

  const int tid  = threadIdx.x;
  const int lane = tid & 63;
  const int wave = tid >> 6;
  const int c    = lane & 15;
  const int g    = lane >> 4;
  const int wq   = wave >> 1;      // q-subtile pair selector
  const int wk   = wave & 1;       // kv half

  // XCD-aware decode: 4 bh per XCD; pair p -> q-tiles (31-p, p).
  const int f     = blockIdx.x;            // 512 blocks
  const int xcd   = f & 7;
  const int inner = f >> 3;                // 0..63
  const int bh    = ((inner >> 4) << 3) | xcd;
  const int p     = inner & 15;
  const int qt_a  = 31 - p;                // 16..31
  const int qt_b  = p;                     // 0..15
  const int nkt_a = qt_a + 1;              // 17..32
  const int nkt_b = qt_b + 1;              // 1..16

  const float CS = 0.18033688011f;         // (1/sqrt(64)) * log2(e)
  const size_t bhoff = (size_t)bh * SEQ * DKK;
  const float* Qb = Qg + bhoff;
  float*       Ob = Og + bhoff;
  const char*  wsb = ws + ((size_t)bh * NKT << 14);

  // prologue: load tile 0 into registers (256 thr x 4 x 16B)
  s16x8 st0 = *(const s16x8*)(wsb + tid * 16);
  s16x8 st1 = *(const s16x8*)(wsb + 4096 + tid * 16);
  s16x8 st2 = *(const s16x8*)(wsb + 8192 + tid * 16);
  s16x8 st3 = *(const s16x8*)(wsb + 12288 + tid * 16);

  // Q fragments: qf[tile][uu][h]; row = qt*64 + (wq*2+uu)*16 + c
  s16x8 qfA[2][2], qfB[2][2];
#pragma unroll
  for (int uu = 0; uu < 2; ++uu)
#pragma unroll
    for (int h = 0; h < 2; ++h) {
      int d0 = h * 32 + g * 8;
      {
        const f32x4* pq = (const f32x4*)(Qb + (size_t)(qt_a * 64 + (wq * 2 + uu) * 16 + c) * DKK + d0);
        f32x4 a = pq[0], b = pq[1];
        s16x8 r;
        r[0]=f2b(a[0]*CS); r[1]=f2b(a[1]*CS); r[2]=f2b(a[2]*CS); r[3]=f2b(a[3]*CS);
        r[4]=f2b(b[0]*CS); r[5]=f2b(b[1]*CS); r[6]=f2b(b[2]*CS); r[7]=f2b(b[3]*CS);
        qfA[uu][h] = r;
      }
      {
        const f32x4* pq = (const f32x4*)(Qb + (size_t)(qt_b * 64 + (wq * 2 + uu) * 16 + c) * DKK + d0);
        f32x4 a = pq[0], b = pq[1];
        s16x8 r;
        r[0]=f2b(a[0]*CS); r[1]=f2b(a[1]*CS); r[2]=f2b(a[2]*CS); r[3]=f2b(a[3]*CS);
        r[4]=f2b(b[0]*CS); r[5]=f2b(b[1]*CS); r[6]=f2b(b[2]*CS); r[7]=f2b(b[3]*CS);
        qfB[uu][h] = r;
      }
    }

  s16x8 ones8;
#pragma unroll
  for (int j = 0; j < 8; ++j) ones8[j] = (short)0x3F80;

  f32x4 OA[2][4] = {}, OB[2][4] = {};
  f32x4 OlA[2] = {}, OlB[2] = {};

  char* Kl = smem;
  char* Vl = smem + 8192;
  char* Pl = smem + TILE_BYTES + wave * 4096;
  // P slot (1KB per (tile,uu)): addr(row,pos) =
  //   row*64 + ((pos*2) ^ ((row&3)<<4) ^ (((row>>2)&1)<<5))
  // write: row=g*4+r, u32 at pos=c*2 -> (g*4+r)*64 + ((c*4)^(r<<4)^((g&1)<<5))
  // read : row=c, 16B at pos=g*8 -> c*64 + ((g*16)^((c&3)<<4)^(((c>>2)&1)<<5))
  const int pwSwz = (c * 4) ^ ((g & 1) << 5);
  const int prOff = c * 64 + ((g * 16) ^ ((c & 3) << 4) ^ (((c >> 2) & 1) << 5));

  for (int kt = 0; kt < nkt_a; ++kt) {
    __syncthreads();                       // (a) prev-iter LDS reads done
    *(s16x8*)(smem + tid * 16)         = st0;
    *(s16x8*)(smem + 4096 + tid * 16)  = st1;
    *(s16x8*)(smem + 8192 + tid * 16)  = st2;
    *(s16x8*)(smem + 12288 + tid * 16) = st3;
    if (kt + 1 < nkt_a) {                  // prefetch next tile into regs
      const char* tn = wsb + ((size_t)(kt + 1) << 14);
      st0 = *(const s16x8*)(tn + tid * 16);
      st1 = *(const s16x8*)(tn + 4096 + tid * 16);
      st2 = *(const s16x8*)(tn + 8192 + tid * 16);
      st3 = *(const s16x8*)(tn + 12288 + tid * 16);
    }
    __syncthreads();                       // (b) staged tile visible

    const bool doB = (kt < nkt_b);

    // K fragments for this wave's kv half (shared by all 4 q-subtiles)
    s16x8 kf[2][2];
#pragma unroll
    for (int sl = 0; sl < 2; ++sl)
#pragma unroll
      for (int h = 0; h < 2; ++h)
        kf[sl][h] = *(const s16x8*)(Kl + swzA((wk * 2 + sl) * 16 + c, h * 32 + g * 8));

    // QK^T
    f32x4 SA[2][2] = {}, SB[2][2] = {};
    __builtin_amdgcn_s_setprio(1);
#pragma unroll
    for (int uu = 0; uu < 2; ++uu)
#pragma unroll
      for (int sl = 0; sl < 2; ++sl)
#pragma unroll
        for (int h = 0; h < 2; ++h)
          SA[uu][sl] = __builtin_amdgcn_mfma_f32_16x16x32_bf16(
              __builtin_bit_cast(bf16x8, qfA[uu][h]),
              __builtin_bit_cast(bf16x8, kf[sl][h]), SA[uu][sl], 0, 0, 0);
    if (doB) {
#pragma unroll
      for (int uu = 0; uu < 2; ++uu)
#pragma unroll
        for (int sl = 0; sl < 2; ++sl)
#pragma unroll
          for (int h = 0; h < 2; ++h)
            SB[uu][sl] = __builtin_amdgcn_mfma_f32_16x16x32_bf16(
                __builtin_bit_cast(bf16x8, qfB[uu][h]),
                __builtin_bit_cast(bf16x8, kf[sl][h]), SB[uu][sl], 0, 0, 0);
    }
    __builtin_amdgcn_s_setprio(0);

    // causal masks (diagonal tiles only)
    if (kt == qt_a) {
#pragma unroll
      for (int uu = 0; uu < 2; ++uu)
#pragma unroll
        for (int sl = 0; sl < 2; ++sl) {
          int kvl = wk * 32 + sl * 16 + c;
#pragma unroll
          for (int r = 0; r < 4; ++r)
            if (kvl > (wq * 2 + uu) * 16 + g * 4 + r) SA[uu][sl][r] = -1e30f;
        }
    }
    if (doB && kt == qt_b) {
#pragma unroll
      for (int uu = 0; uu < 2; ++uu)
#pragma unroll
        for (int sl = 0; sl < 2; ++sl) {
          int kvl = wk * 32 + sl * 16 + c;
#pragma unroll
          for (int r = 0; r < 4; ++r)
            if (kvl > (wq * 2 + uu) * 16 + g * 4 + r) SB[uu][sl][r] = -1e30f;
        }
    }

    // exp2-direct P, packed 2 bf16 per ds_write_b32 (pos = c*2+sl)
#pragma unroll
    for (int uu = 0; uu < 2; ++uu)
#pragma unroll
      for (int r = 0; r < 4; ++r) {
        uint32_t w = (uint32_t)f2b(exp2f(SA[uu][0][r]))
                   | ((uint32_t)f2b(exp2f(SA[uu][1][r])) << 16);
        *(uint32_t*)(Pl + uu * 1024 + (g * 4 + r) * 64 + (pwSwz ^ (r << 4))) = w;
      }
    if (doB) {
#pragma unroll
      for (int uu = 0; uu < 2; ++uu)
#pragma unroll
        for (int r = 0; r < 4; ++r) {
          uint32_t w = (uint32_t)f2b(exp2f(SB[uu][0][r]))
                     | ((uint32_t)f2b(exp2f(SB[uu][1][r])) << 16);
          *(uint32_t*)(Pl + (2 + uu) * 1024 + (g * 4 + r) * 64 + (pwSwz ^ (r << 4))) = w;
        }
    }

    // PV: V frags shared across all active q-subtiles
    s16x8 paA0 = *(const s16x8*)(Pl + 0 * 1024 + prOff);
    s16x8 paA1 = *(const s16x8*)(Pl + 1 * 1024 + prOff);
    s16x8 paB0, paB1;
    if (doB) {
      paB0 = *(const s16x8*)(Pl + 2 * 1024 + prOff);
      paB1 = *(const s16x8*)(Pl + 3 * 1024 + prOff);
    }
    __builtin_amdgcn_s_setprio(1);
#pragma unroll
    for (int t = 0; t < 4; ++t) {
      s16x8 vb = *(const s16x8*)(Vl + swzV(t * 16 + c, wk * 32 + g * 8));
      OA[0][t] = __builtin_amdgcn_mfma_f32_16x16x32_bf16(
          __builtin_bit_cast(bf16x8, paA0), __builtin_bit_cast(bf16x8, vb), OA[0][t], 0, 0, 0);
      OA[1][t] = __builtin_amdgcn_mfma_f32_16x16x32_bf16(
          __builtin_bit_cast(bf16x8, paA1), __builtin_bit_cast(bf16x8, vb), OA[1][t], 0, 0, 0);
      if (doB) {
        OB[0][t] = __builtin_amdgcn_mfma_f32_16x16x32_bf16(
            __builtin_bit_cast(bf16x8, paB0), __builtin_bit_cast(bf16x8, vb), OB[0][t], 0, 0, 0);
        OB[1][t] = __builtin_amdgcn_mfma_f32_16x16x32_bf16(
            __builtin_bit_cast(bf16x8, paB1), __builtin_bit_cast(bf16x8, vb), OB[1][t], 0, 0, 0);
      }
    }
    OlA[0] = __builtin_amdgcn_mfma_f32_16x16x32_bf16(
        __builtin_bit_cast(bf16x8, paA0), __builtin_bit_cast(bf16x8, ones8), OlA[0], 0, 0, 0);
    OlA[1] = __builtin_amdgcn_mfma_f32_16x16x32_bf16(
        __builtin_bit_cast(bf16x8, paA1), __builtin_bit_cast(bf16x8, ones8), OlA[1], 0, 0, 0);
    if (doB) {
      OlB[0] = __builtin_amdgcn_mfma_f32_16x16x32_bf16(
          __builtin_bit_cast(bf16x8, paB0), __builtin_bit_cast(bf16x8, ones8), OlB[0], 0, 0, 0);
      OlB[1] = __builtin_amdgcn_mfma_f32_16x16x32_bf16(
          __builtin_bit_cast(bf16x8, paB1), __builtin_bit_cast(bf16x8, ones8), OlB[1], 0, 0, 0);
    }
    __builtin_amdgcn_s_setprio(0);
  }

  // epilogue: reduce kv halves via LDS, normalize, store
  __syncthreads();
  auto reduce_store = [&](f32x4 (&O)[2][4], f32x4 (&Ol)[2], int qt) {
    if (wk == 1) {
#pragma unroll
      for (int uu = 0; uu < 2; ++uu) {
#pragma unroll
        for (int t = 0; t < 4; ++t)
          *(f32x4*)(smem + ((((wq * 2 + uu) * 5 + t) * 64 + lane) << 4)) = O[uu][t];
        *(f32x4*)(smem + ((((wq * 2 + uu) * 5 + 4) * 64 + lane) << 4)) = Ol[uu];
      }
    }
    __syncthreads();
    if (wk == 0) {
#pragma unroll
      for (int uu = 0; uu < 2; ++uu) {
        f32x4 l2 = Ol[uu] + *(const f32x4*)(smem + ((((wq * 2 + uu) * 5 + 4) * 64 + lane) << 4));
        f32x4 inv;
#pragma unroll
        for (int r = 0; r < 4; ++r) inv[r] = 1.f / l2[r];
#pragma unroll
        for (int t = 0; t < 4; ++t) {
          f32x4 o = O[uu][t] + *(const f32x4*)(smem + ((((wq * 2 + uu) * 5 + t) * 64 + lane) << 4));
#pragma unroll
          for (int r = 0; r < 4; ++r) {
            int qrow = qt * 64 + (wq * 2 + uu) * 16 + g * 4 + r;
            Ob[(size_t)qrow * DKK + t * 16 + c] = o[r] * inv[r];
          }
        }
      }
    }
    __syncthreads();
  };
  reduce_store(OA, OlA, qt_a);
  reduce_store(OB, OlB, qt_b);
}

// ---------------- fallback: self-staging (only if ws too small) -------------
__global__ __launch_bounds__(256, 2)
void attn_fwd_fb(const float* __restrict__ Qg, const float* __restrict__ Kg,
                 const float* __restrict__ Vg, float* __restrict__ Og) {
  __shared__ __align__(16) char smem[8192 + 8192 + 8 * 2048];
  char* Kl = smem;
  char* Vl = smem + 8192;
  const int tid  = threadIdx.x;
  const int lane = tid & 63;
  const int wave = tid >> 6;
  const int c    = lane & 15;
  const int g    = lane >> 4;
  const int f    = blockIdx.x;
  const int xcd  = f & 7;
  const int inner= f >> 3;
  const int bh   = ((inner >> 4) << 3) | xcd;
  const int qt   = 15 - (inner & 15);
  const float CS = 0.18033688011f;
  const size_t bhoff = (size_t)bh * SEQ * DKK;
  const float* Qb = Qg + bhoff;
  const float* Kb = Kg + bhoff;
  const float* Vb = Vg + bhoff;
  float*       Ob = Og + bhoff;
  s16x8 qf[2][2];
#pragma unroll
  for (int u = 0; u < 2; ++u) {
    int qrow = qt * 128 + wave * 32 + u * 16 + c;
#pragma unroll
    for (int h = 0; h < 2; ++h) {
      int d0 = h * 32 + g * 8;
      const f32x4* pq = (const f32x4*)(Qb + (size_t)qrow * DKK + d0);
      f32x4 a = pq[0], b = pq[1];
      s16x8 r;
      r[0]=f2b(a[0]*CS); r[1]=f2b(a[1]*CS); r[2]=f2b(a[2]*CS); r[3]=f2b(a[3]*CS);
      r[4]=f2b(b[0]*CS); r[5]=f2b(b[1]*CS); r[6]=f2b(b[2]*CS); r[7]=f2b(b[3]*CS);
      qf[u][h] = r;
    }
  }
  f32x4 O[2][4] = {};
  float m[2][4], l[2][4];
#pragma unroll
  for (int u = 0; u < 2; ++u)
#pragma unroll
    for (int r = 0; r < 4; ++r) { m[u][r] = -1e30f; l[u][r] = 0.f; }
  const int nkt = 2 * qt + 2;
  for (int kt = 0; kt < nkt; ++kt) {
    __syncthreads();
    {
      int col4 = tid & 15, rq = tid >> 4;
#pragma unroll
      for (int ii = 0; ii < 4; ++ii) {
        int row = ii * 16 + rq;
        f32x4 v = *(const f32x4*)(Kb + (size_t)(kt * KVB + row) * DKK + col4 * 4);
        s16x4 w; w[0]=f2b(v[0]); w[1]=f2b(v[1]); w[2]=f2b(v[2]); w[3]=f2b(v[3]);
        *(s16x4*)(Kl + swzA(row, col4 * 4)) = w;
      }
      int d0 = (tid & 15) * 4, kv0 = (tid >> 4) * 4;
      f32x4 vv[4];
#pragma unroll
      for (int r2 = 0; r2 < 4; ++r2)
        vv[r2] = *(const f32x4*)(Vb + (size_t)(kt * KVB + kv0 + r2) * DKK + d0);
#pragma unroll
      for (int j = 0; j < 4; ++j) {
        s16x4 w; w[0]=f2b(vv[0][j]); w[1]=f2b(vv[1][j]); w[2]=f2b(vv[2][j]); w[3]=f2b(vv[3][j]);
        *(s16x4*)(Vl + swzV(d0 + j, kv0)) = w;
      }
    }
    __syncthreads();
    f32x4 S[2][4] = {};
#pragma unroll
    for (int s = 0; s < 4; ++s)
#pragma unroll
      for (int h = 0; h < 2; ++h) {
        s16x8 kf = *(const s16x8*)(Kl + swzA(s * 16 + c, h * 32 + g * 8));
#pragma unroll
        for (int u = 0; u < 2; ++u)
          S[u][s] = __builtin_amdgcn_mfma_f32_16x16x32_bf16(
              __builtin_bit_cast(bf16x8, qf[u][h]),
              __builtin_bit_cast(bf16x8, kf), S[u][s], 0, 0, 0);
      }
    if (kt >= nkt - 2) {
#pragma unroll
      for (int u = 0; u < 2; ++u) {
        int qrb = qt * 128 + wave * 32 + u * 16 + g * 4;
#pragma unroll
        for (int s = 0; s < 4; ++s) {
          int kv = kt * KVB + s * 16 + c;
#pragma unroll
          for (int r = 0; r < 4; ++r)
            if (kv > qrb + r) S[u][s][r] = -1e30f;
        }
      }
    }
#pragma unroll
    for (int u = 0; u < 2; ++u) {
      char* Pl = smem + 16384 + (wave * 2 + u) * 2048;
#pragma unroll
      for (int r = 0; r < 4; ++r) {
        float t0 = fmaxf(fmaxf(S[u][0][r], S[u][1][r]),
                         fmaxf(S[u][2][r], S[u][3][r]));
#pragma unroll
        for (int off = 1; off <= 8; off <<= 1)
          t0 = fmaxf(t0, __shfl_xor(t0, off));
        float mn   = fmaxf(m[u][r], t0);
        float corr = exp2f(m[u][r] - mn);
        float ps = 0.f;
#pragma unroll
        for (int s = 0; s < 4; ++s) {
          float pv = exp2f(S[u][s][r] - mn);
          ps += pv;
          *(unsigned short*)(Pl + swzA(g * 4 + r, s * 16 + c)) = f2b(pv);
        }
#pragma unroll
        for (int off = 1; off <= 8; off <<= 1)
          ps += __shfl_xor(ps, off);
        l[u][r] = l[u][r] * corr + ps;
        m[u][r] = mn;
#pragma unroll
        for (int t = 0; t < 4; ++t) O[u][t][r] *= corr;
      }
    }
#pragma unroll
    for (int ch = 0; ch < 2; ++ch) {
      s16x8 pa[2];
#pragma unroll
      for (int u = 0; u < 2; ++u)
        pa[u] = *(const s16x8*)(smem + 16384 + (wave * 2 + u) * 2048
                                + swzA(c, ch * 32 + g * 8));
#pragma unroll
      for (int t = 0; t < 4; ++t) {
        s16x8 vb = *(const s16x8*)(Vl + swzV(t * 16 + c, ch * 32 + g * 8));
#pragma unroll
        for (int u = 0; u < 2; ++u)
          O[u][t] = __builtin_amdgcn_mfma_f32_16x16x32_bf16(
              __builtin_bit_cast(bf16x8, pa[u]),
              __builtin_bit_cast(bf16x8, vb), O[u][t], 0, 0, 0);
      }
    }
  }
#pragma unroll
  for (int u = 0; u < 2; ++u)
#pragma unroll
    for (int r = 0; r < 4; ++r) {
      int qrow = qt * 128 + wave * 32 + u * 16 + g * 4 + r;
      float inv = 1.f / l[u][r];
#pragma unroll
      for (int t = 0; t < 4; ++t)
        Ob[(size_t)qrow * DKK + t * 16 + c] = O[u][t][r] * inv;
    }
}

extern "C" void kernel_launch(void* const* d_in, const int* in_sizes, int n_in,
                              void* d_out, int out_size, void* d_ws, size_t ws_size,
                              hipStream_t stream) {
  const float* Q = (const float*)d_in[0];
  const float* K = (const float*)d_in[1];
  const float* V = (const float*)d_in[2];
  float* O = (float*)d_out;
  (void)in_sizes; (void)n_in; (void)out_size;
  if (ws_size >= WS_NEED) {
    char* ws = (char*)d_ws;
    prep_kv<<<dim3(32 * NKT), dim3(256), 0, stream>>>(K, V, ws);
    attn_fwd8<<<dim3(512), dim3(256), 0, stream>>>(Q, ws, O);
  } else {
    attn_fwd_fb<<<dim3(512), dim3(256), 0, stream>>>(Q, K, V, O);
  }
}